// Round 5
// baseline (180.775 us; speedup 1.0000x reference)
//
#include <hip/hip_runtime.h>

// CapsNet conv + dynamic routing, single fused kernel (MI355X / gfx950).
// grid = 192 blocks x 1024 threads; each block owns 3 consecutive pixels.
// All 3 pixels' convs run first (votes in acc[3][4][4], 192 VGPRs), then the
// 3 routings execute interleaved in one instruction stream (3x ILP on the
// latency chains, barriers amortized 3x). __launch_bounds__(1024,4) grants
// the full 512-reg budget -> no scratch spills (R4's 36 MB spill traffic).
//
// Lane decomposition (l = lane, q = l>>4, il = l&15), wave (wf, wi):
//   acc[p][tf][ti].r = votes[ i = 64*wi+16*ti+il ][ f = 64*wf+16*tf+4*q+r ]
//   c = 8*wf + 2*tf + (q>>1)   (capsule),  n = 4*(q&1) + r

#define BS 16
#define CI 256
#define CO 32
#define NO 8
#define HI 20
#define WI 20
#define HO 6
#define WO 6
#define NPIX 36
#define NTAP 81
#define XP 104          // k pitch (bf16), 2-way banks (free)
#define PPB 3
#define NBLK 192

typedef __attribute__((ext_vector_type(8))) short bf16x8;
typedef __attribute__((ext_vector_type(4))) float f32x4;

__device__ __forceinline__ ushort f2bf(float x) {
    union { float f; unsigned u; } v; v.f = x;
    unsigned r = v.u + 0x7FFFu + ((v.u >> 16) & 1u);   // RNE
    return (ushort)(r >> 16);
}

__global__ __launch_bounds__(1024, 4) void caps_kernel(
    const float* __restrict__ x,     // [16,256,1,20,20]
    const float* __restrict__ Wt,    // [256,1,9,9]
    const float* __restrict__ bias,  // [32,8,1,1]
    float* __restrict__ out)         // [16,32,8,6,6]
{
    // LDS overlay: conv phase uses xw+wl (106496 B); routing overlays its
    // arrays onto the (dead) xw region.
    __shared__ __align__(16) char ldsbuf[106496];
    ushort* xw  = (ushort*)ldsbuf;                 // [256][104] bf16
    ushort* wl  = (ushort*)(ldsbuf + 53248);       // [256][104] bf16
    float*  smx = (float*)ldsbuf;                  // [3][4][256] softmax partials
    float*  pre = (float*)(ldsbuf + 12288);        // [3][4][256] preact partials
    float*  outb= (float*)(ldsbuf + 24576);        // [3][256]

    const int t   = threadIdx.x, blk = blockIdx.x;
    const int b   = blk / 12;
    const int hw0 = (blk % 12) * 3;

    const int wid = t >> 6, l = t & 63;
    const int q = l >> 4, il = l & 15;
    const int wf = wid >> 2, wi = wid & 3;

    // ---- stage W (k-major, pitch 104) + zero pads for both tiles
    for (int p = t; p < CO * NO * NTAP; p += 1024) {
        int f = p / NTAP, k = p - f * NTAP;
        wl[f * XP + k] = f2bf(Wt[p]);
    }
    {
        int i = t >> 2, s4 = t & 3;
        #pragma unroll
        for (int j = 0; j < 6; ++j) {
            int k = NTAP + s4 * 6 + j;
            if (k < XP) { xw[i * XP + k] = 0; wl[i * XP + k] = 0; }
        }
    }
    // ---- stage x for pixel 0
    {
        const int h = hw0 / WO, w = hw0 % WO;
        for (int p = t; p < CI * 9; p += 1024) {
            int i = p / 9, kh = p - i * 9;
            const float* src = x + ((b * CI + i) * HI + (2 * h + kh)) * WI + 2 * w;
            #pragma unroll
            for (int kw = 0; kw < 9; ++kw)
                xw[i * XP + kh * 9 + kw] = f2bf(src[kw]);
        }
    }

    f32x4 bias_v[4];
    #pragma unroll
    for (int tf = 0; tf < 4; ++tf)
        bias_v[tf] = *(const f32x4*)&bias[(wf * 8 + tf * 2 + (q >> 1)) * 8 + 4 * (q & 1)];

    // ---- conv all 3 pixels into resident accumulators
    f32x4 acc[3][4][4];
    #pragma unroll
    for (int p = 0; p < 3; ++p)
        #pragma unroll
        for (int tf = 0; tf < 4; ++tf)
            #pragma unroll
            for (int ti = 0; ti < 4; ++ti)
                acc[p][tf][ti] = (f32x4){0.f, 0.f, 0.f, 0.f};

    #pragma unroll
    for (int pix = 0; pix < 3; ++pix) {
        __syncthreads();   // staging visible
        #pragma unroll
        for (int ks = 0; ks < 3; ++ks) {
            const int ko = ks * 32 + q * 8;
            bf16x8 af[4], bv[4];
            #pragma unroll
            for (int tf = 0; tf < 4; ++tf)
                af[tf] = *(const bf16x8*)&wl[(wf * 64 + tf * 16 + il) * XP + ko];
            #pragma unroll
            for (int ti = 0; ti < 4; ++ti)
                bv[ti] = *(const bf16x8*)&xw[(wi * 64 + ti * 16 + il) * XP + ko];
            #pragma unroll
            for (int tf = 0; tf < 4; ++tf)
                #pragma unroll
                for (int ti = 0; ti < 4; ++ti)
                    acc[pix][tf][ti] = __builtin_amdgcn_mfma_f32_16x16x32_bf16(
                        af[tf], bv[ti], acc[pix][tf][ti], 0, 0, 0);
        }
        __syncthreads();   // xw reads done
        if (pix < 2) {
            const int hwn = hw0 + pix + 1;
            const int h = hwn / WO, w = hwn % WO;
            for (int p = t; p < CI * 9; p += 1024) {
                int i = p / 9, kh = p - i * 9;
                const float* src = x + ((b * CI + i) * HI + (2 * h + kh)) * WI + 2 * w;
                #pragma unroll
                for (int kw = 0; kw < 9; ++kw)
                    xw[i * XP + kh * 9 + kw] = f2bf(src[kw]);
            }
        }
    }
    // (last conv's trailing barrier separates xw reads from routing overlay writes)

    // ---- dynamic routing: 3 iterations, 3 pixels interleaved
    float lg[3][4][4];
    #pragma unroll
    for (int p = 0; p < 3; ++p)
        #pragma unroll
        for (int tf = 0; tf < 4; ++tf)
            #pragma unroll
            for (int ti = 0; ti < 4; ++ti) lg[p][tf][ti] = 0.f;

    #pragma unroll
    for (int it = 0; it < 3; ++it) {
        // --- route = softmax over c, all pixels
        float route[3][4][4];
        if (it == 0) {
            #pragma unroll
            for (int p = 0; p < 3; ++p)
                #pragma unroll
                for (int tf = 0; tf < 4; ++tf)
                    #pragma unroll
                    for (int ti = 0; ti < 4; ++ti) route[p][tf][ti] = 0.03125f;
        } else {
            float e[3][4][4], srow[3][4];
            #pragma unroll
            for (int p = 0; p < 3; ++p)
                #pragma unroll
                for (int ti = 0; ti < 4; ++ti) srow[p][ti] = 0.f;
            #pragma unroll
            for (int p = 0; p < 3; ++p)
                #pragma unroll
                for (int tf = 0; tf < 4; ++tf)
                    #pragma unroll
                    for (int ti = 0; ti < 4; ++ti) {
                        e[p][tf][ti] = __expf(lg[p][tf][ti]);
                        srow[p][ti] += e[p][tf][ti];
                    }
            #pragma unroll
            for (int p = 0; p < 3; ++p)
                #pragma unroll
                for (int ti = 0; ti < 4; ++ti)
                    srow[p][ti] += __shfl_xor(srow[p][ti], 32, 64);
            if (q == 0) {
                #pragma unroll
                for (int p = 0; p < 3; ++p)
                    #pragma unroll
                    for (int ti = 0; ti < 4; ++ti)
                        smx[p * 1024 + wf * 256 + wi * 64 + ti * 16 + il] = srow[p][ti];
            }
            __syncthreads();
            #pragma unroll
            for (int p = 0; p < 3; ++p) {
                float rtot[4];
                #pragma unroll
                for (int ti = 0; ti < 4; ++ti) {
                    int i = p * 1024 + wi * 64 + ti * 16 + il;
                    rtot[ti] = __builtin_amdgcn_rcpf(
                        smx[i] + smx[256 + i] + smx[512 + i] + smx[768 + i]);
                }
                #pragma unroll
                for (int tf = 0; tf < 4; ++tf)
                    #pragma unroll
                    for (int ti = 0; ti < 4; ++ti)
                        route[p][tf][ti] = e[p][tf][ti] * rtot[ti];
            }
        }

        // --- preact partials; reduce over in-lane ti, then il butterfly
        float pp[3][4][4];
        #pragma unroll
        for (int p = 0; p < 3; ++p)
            #pragma unroll
            for (int tf = 0; tf < 4; ++tf)
                #pragma unroll
                for (int r = 0; r < 4; ++r)
                    pp[p][tf][r] = route[p][tf][0] * acc[p][tf][0][r]
                                 + route[p][tf][1] * acc[p][tf][1][r]
                                 + route[p][tf][2] * acc[p][tf][2][r]
                                 + route[p][tf][3] * acc[p][tf][3][r];
        #pragma unroll
        for (int m = 1; m <= 8; m <<= 1)
            #pragma unroll
            for (int p = 0; p < 3; ++p)
                #pragma unroll
                for (int tf = 0; tf < 4; ++tf)
                    #pragma unroll
                    for (int r = 0; r < 4; ++r)
                        pp[p][tf][r] += __shfl_xor(pp[p][tf][r], m, 64);
        if (il == 0) {
            #pragma unroll
            for (int p = 0; p < 3; ++p)
                #pragma unroll
                for (int tf = 0; tf < 4; ++tf) {
                    int c = wf * 8 + tf * 2 + (q >> 1);
                    f32x4 vv = {pp[p][tf][0], pp[p][tf][1], pp[p][tf][2], pp[p][tf][3]};
                    *(f32x4*)&pre[p * 1024 + wi * 256 + c * 8 + (q & 1) * 4] = vv;
                }
        }
        __syncthreads();

        // --- per-lane redundant squash
        float av[3][4][4];
        #pragma unroll
        for (int p = 0; p < 3; ++p)
            #pragma unroll
            for (int tf = 0; tf < 4; ++tf) {
                const int c8 = (wf * 8 + tf * 2 + (q >> 1)) * 8 + (q & 1) * 4;
                f32x4 p0 = *(const f32x4*)&pre[p * 1024 + c8];
                f32x4 p1 = *(const f32x4*)&pre[p * 1024 + 256 + c8];
                f32x4 p2 = *(const f32x4*)&pre[p * 1024 + 512 + c8];
                f32x4 p3 = *(const f32x4*)&pre[p * 1024 + 768 + c8];
                float s[4], sq4 = 0.f;
                #pragma unroll
                for (int r = 0; r < 4; ++r) {
                    s[r] = bias_v[tf][r] + p0[r] + p1[r] + p2[r] + p3[r];
                    sq4 += s[r] * s[r];
                }
                float sq = sq4 + __shfl_xor(sq4, 16, 64);
                float scale = __builtin_amdgcn_sqrtf(sq) * __builtin_amdgcn_rcpf(1.f + sq);
                #pragma unroll
                for (int r = 0; r < 4; ++r) av[p][tf][r] = s[r] * scale;
            }

        if (it < 2) {
            // --- distances -> logits
            #pragma unroll
            for (int p = 0; p < 3; ++p)
                #pragma unroll
                for (int tf = 0; tf < 4; ++tf)
                    #pragma unroll
                    for (int ti = 0; ti < 4; ++ti) {
                        float d = acc[p][tf][ti][0] * av[p][tf][0]
                                + acc[p][tf][ti][1] * av[p][tf][1]
                                + acc[p][tf][ti][2] * av[p][tf][2]
                                + acc[p][tf][ti][3] * av[p][tf][3];
                        d += __shfl_xor(d, 16, 64);
                        lg[p][tf][ti] += d;
                    }
        } else if (wi == 0 && il == 0) {
            #pragma unroll
            for (int p = 0; p < 3; ++p)
                #pragma unroll
                for (int tf = 0; tf < 4; ++tf) {
                    const int c8 = (wf * 8 + tf * 2 + (q >> 1)) * 8 + (q & 1) * 4;
                    #pragma unroll
                    for (int r = 0; r < 4; ++r)
                        outb[p * 256 + c8 + r] = av[p][tf][r];
                }
        }
    }

    __syncthreads();
    if (t < PPB * 256) {
        const int cn = t / 3, pix = t - cn * 3;
        out[(b * 256 + cn) * NPIX + hw0 + pix] = outb[pix * 256 + cn];
    }
}

extern "C" void kernel_launch(void* const* d_in, const int* in_sizes, int n_in,
                              void* d_out, int out_size, void* d_ws, size_t ws_size,
                              hipStream_t stream) {
    const float* x    = (const float*)d_in[0];
    const float* Wt   = (const float*)d_in[1];
    const float* bias = (const float*)d_in[2];
    float* out = (float*)d_out;
    caps_kernel<<<NBLK, 1024, 0, stream>>>(x, Wt, bias, out);
}

// Round 6
// 68.565 us; speedup vs baseline: 2.6365x; 2.6365x over previous
//
#include <hip/hip_runtime.h>

// CapsNet conv + dynamic routing, single fused kernel (MI355X / gfx950).
// One block (1024 thr = 16 waves) per pixel; votes^T in the MFMA accumulator
// (64 AGPR). Hard constraint: 16-wave block => 128 regs/thread cap, so the
// routing working set must fit 64 VGPRs (R2 shape, verified spill-free).
// This revision: coalesced float4 staging (replaces the 57-line/wave-inst
// scalar scatter), XCD-local block->image mapping, one fewer barrier,
// it0 shortcut, fast rcp/sqrt.
//
// Lane decomposition (l = lane, q = l>>4, il = l&15), wave (wf, wi):
//   acc[tf][ti].r = votes[ i = 64*wi+16*ti+il ][ f = 64*wf+16*tf+4*q+r ]
//   c = 8*wf + 2*tf + (q>>1)   (capsule),  n = 4*(q&1) + r

#define BS 16
#define CI 256
#define CO 32
#define NO 8
#define HI 20
#define WI 20
#define HO 6
#define WO 6
#define NPIX 36
#define NTAP 81
#define XP 104          // k pitch (bf16), 2-way banks (free)
#define NBLK 576

typedef __attribute__((ext_vector_type(8))) short bf16x8;
typedef __attribute__((ext_vector_type(4))) float f32x4;

__device__ __forceinline__ ushort f2bf(float x) {
    union { float f; unsigned u; } v; v.f = x;
    unsigned r = v.u + 0x7FFFu + ((v.u >> 16) & 1u);   // RNE
    return (ushort)(r >> 16);
}

__global__ __launch_bounds__(1024) void caps_kernel(
    const float* __restrict__ x,     // [16,256,1,20,20]
    const float* __restrict__ Wt,    // [256,1,9,9]
    const float* __restrict__ bias,  // [32,8,1,1]
    float* __restrict__ out)         // [16,32,8,6,6]
{
    __shared__ __align__(16) ushort xw[CI * XP];        // 53248 B
    __shared__ __align__(16) ushort wl[CO * NO * XP];   // 53248 B
    __shared__ __align__(16) float  smx[4 * 256];       // softmax partials [wf][i]
    __shared__ __align__(16) float  pre[4 * 256];       // preact partials [wi][c*8+n]
    __shared__ __align__(16) float  act[256];           // activation broadcast

    const int t   = threadIdx.x, blk = blockIdx.x;
    // XCD-local mapping: blocks with the same (blk mod 8) land on the same
    // XCD (round-robin dispatch); b = blk&15 keeps each XCD's L2 serving
    // only 2 of the 16 images' x data.
    const int b   = blk & 15;
    const int hw  = blk >> 4;          // 0..35
    const int h   = hw / WO, w = hw % WO;
    const int w2  = 2 * w;

    const int wid = t >> 6, l = t & 63;
    const int q = l >> 4, il = l & 15;
    const int wf = wid >> 2, wi = wid & 3;

    // ---- stage W (k-major, pitch 104): coalesced over p, ~20 elems/thread
    for (int p = t; p < CO * NO * NTAP; p += 1024) {
        int f = p / NTAP, k = p - f * NTAP;
        wl[f * XP + k] = f2bf(Wt[p]);
    }
    // ---- zero pads k in [81,104) for both tiles (4 threads per row)
    {
        int i = t >> 2, s4 = t & 3;
        #pragma unroll
        for (int j = 0; j < 6; ++j) {
            int k = NTAP + s4 * 6 + j;
            if (k < XP) { xw[i * XP + k] = 0; wl[i * XP + k] = 0; }
        }
    }
    // ---- stage x window, coalesced: float4 quads over cols 0..15, then the
    // col-16 tail quad when the window reaches past col 15 (w >= 4).
    // idx = (i*9 + kh)*4 + q4 : consecutive lanes read consecutive 16B.
    #pragma unroll
    for (int pass = 0; pass < 9; ++pass) {
        int idx = pass * 1024 + t;
        int q4 = idx & 3, r = idx >> 2;
        int kh = r % 9, i = r / 9;
        float4 v = *(const float4*)(x + ((b * CI + i) * HI + (2 * h + kh)) * WI + 4 * q4);
        const float* ve = &v.x;
        #pragma unroll
        for (int e = 0; e < 4; ++e) {
            int kw = 4 * q4 + e - w2;
            if ((unsigned)kw < 9u) xw[i * XP + kh * 9 + kw] = f2bf(ve[e]);
        }
    }
    if (w >= 4) {
        for (int r = t; r < CI * 9; r += 1024) {
            int kh = r % 9, i = r / 9;
            float4 v = *(const float4*)(x + ((b * CI + i) * HI + (2 * h + kh)) * WI + 16);
            const float* ve = &v.x;
            #pragma unroll
            for (int e = 0; e < 4; ++e) {
                int kw = 16 + e - w2;
                if ((unsigned)kw < 9u) xw[i * XP + kh * 9 + kw] = f2bf(ve[e]);
            }
        }
    }

    const float bias_r = (t < 256) ? bias[t] : 0.f;
    __syncthreads();

    // ---- conv via MFMA: votes^T
    f32x4 acc[4][4];
    #pragma unroll
    for (int tf = 0; tf < 4; ++tf)
        #pragma unroll
        for (int ti = 0; ti < 4; ++ti)
            acc[tf][ti] = (f32x4){0.f, 0.f, 0.f, 0.f};

    #pragma unroll
    for (int ks = 0; ks < 3; ++ks) {
        const int ko = ks * 32 + q * 8;
        bf16x8 af[4], bv[4];
        #pragma unroll
        for (int tf = 0; tf < 4; ++tf)
            af[tf] = *(const bf16x8*)&wl[(wf * 64 + tf * 16 + il) * XP + ko];
        #pragma unroll
        for (int ti = 0; ti < 4; ++ti)
            bv[ti] = *(const bf16x8*)&xw[(wi * 64 + ti * 16 + il) * XP + ko];
        #pragma unroll
        for (int tf = 0; tf < 4; ++tf)
            #pragma unroll
            for (int ti = 0; ti < 4; ++ti)
                acc[tf][ti] = __builtin_amdgcn_mfma_f32_16x16x32_bf16(
                    af[tf], bv[ti], acc[tf][ti], 0, 0, 0);
    }
    // No barrier here: routing uses separate LDS buffers (smx/pre/act), so
    // late conv readers of xw/wl cannot race them.

    // ---- dynamic routing, 3 iterations (math verbatim from verified R2)
    float lg[4][4];
    #pragma unroll
    for (int tf = 0; tf < 4; ++tf)
        #pragma unroll
        for (int ti = 0; ti < 4; ++ti) lg[tf][ti] = 0.f;

    #pragma unroll
    for (int it = 0; it < 3; ++it) {
        // --- preact partials pp[tf][r]
        float pp[4][4];
        if (it == 0) {
            // route uniform = 1/32: pp = (sum over ti) * (1/32)
            #pragma unroll
            for (int tf = 0; tf < 4; ++tf)
                #pragma unroll
                for (int r = 0; r < 4; ++r)
                    pp[tf][r] = (acc[tf][0][r] + acc[tf][1][r]
                               + acc[tf][2][r] + acc[tf][3][r]) * 0.03125f;
        } else {
            // route = softmax over c
            float e[4][4], srow[4] = {0.f, 0.f, 0.f, 0.f};
            #pragma unroll
            for (int tf = 0; tf < 4; ++tf)
                #pragma unroll
                for (int ti = 0; ti < 4; ++ti) {
                    e[tf][ti] = __expf(lg[tf][ti]);
                    srow[ti] += e[tf][ti];
                }
            #pragma unroll
            for (int ti = 0; ti < 4; ++ti)
                srow[ti] += __shfl_xor(srow[ti], 32, 64);   // other c-half (q>>1)
            if (q == 0) {
                #pragma unroll
                for (int ti = 0; ti < 4; ++ti)
                    smx[wf * 256 + wi * 64 + ti * 16 + il] = srow[ti];
            }
            __syncthreads();
            float rtot[4];
            #pragma unroll
            for (int ti = 0; ti < 4; ++ti) {
                int i = wi * 64 + ti * 16 + il;
                rtot[ti] = __builtin_amdgcn_rcpf(
                    smx[i] + smx[256 + i] + smx[512 + i] + smx[768 + i]);
            }
            float route[4][4];
            #pragma unroll
            for (int tf = 0; tf < 4; ++tf)
                #pragma unroll
                for (int ti = 0; ti < 4; ++ti) route[tf][ti] = e[tf][ti] * rtot[ti];
            #pragma unroll
            for (int tf = 0; tf < 4; ++tf)
                #pragma unroll
                for (int r = 0; r < 4; ++r)
                    pp[tf][r] = route[tf][0] * acc[tf][0][r] + route[tf][1] * acc[tf][1][r]
                              + route[tf][2] * acc[tf][2][r] + route[tf][3] * acc[tf][3][r];
        }

        // --- reduce over il lanes (16 i's), write per-wi partials
        #pragma unroll
        for (int m = 1; m <= 8; m <<= 1)
            #pragma unroll
            for (int tf = 0; tf < 4; ++tf)
                #pragma unroll
                for (int r = 0; r < 4; ++r)
                    pp[tf][r] += __shfl_xor(pp[tf][r], m, 64);
        if (il == 0) {
            #pragma unroll
            for (int tf = 0; tf < 4; ++tf) {
                int c = wf * 8 + tf * 2 + (q >> 1);
                f32x4 vv = {pp[tf][0], pp[tf][1], pp[tf][2], pp[tf][3]};
                *(f32x4*)&pre[wi * 256 + c * 8 + (q & 1) * 4] = vv;
            }
        }
        __syncthreads();

        // --- finish preact + squash (threads 0..255), broadcast act
        if (t < 256) {
            float s = bias_r + pre[t] + pre[256 + t] + pre[512 + t] + pre[768 + t];
            float sq = s * s;
            sq += __shfl_xor(sq, 1, 64);
            sq += __shfl_xor(sq, 2, 64);
            sq += __shfl_xor(sq, 4, 64);
            float a = s * __builtin_amdgcn_sqrtf(sq) * __builtin_amdgcn_rcpf(1.f + sq);
            if (it == 2) {
                int c = t >> 3, n = t & 7;
                out[(((b * CO + c) * NO + n) * HO + h) * WO + w] = a;
            } else {
                act[t] = a;
            }
        }
        __syncthreads();

        // --- distances -> logits (skip on last iter)
        if (it < 2) {
            #pragma unroll
            for (int tf = 0; tf < 4; ++tf) {
                int c = wf * 8 + tf * 2 + (q >> 1);
                f32x4 av = *(const f32x4*)&act[c * 8 + (q & 1) * 4];
                #pragma unroll
                for (int ti = 0; ti < 4; ++ti) {
                    float d = acc[tf][ti][0] * av[0] + acc[tf][ti][1] * av[1]
                            + acc[tf][ti][2] * av[2] + acc[tf][ti][3] * av[3];
                    d += __shfl_xor(d, 16, 64);
                    lg[tf][ti] += d;
                }
            }
        }
    }
}

extern "C" void kernel_launch(void* const* d_in, const int* in_sizes, int n_in,
                              void* d_out, int out_size, void* d_ws, size_t ws_size,
                              hipStream_t stream) {
    const float* x    = (const float*)d_in[0];
    const float* Wt   = (const float*)d_in[1];
    const float* bias = (const float*)d_in[2];
    float* out = (float*)d_out;
    caps_kernel<<<NBLK, 1024, 0, stream>>>(x, Wt, bias, out);
}

// Round 7
// 48.315 us; speedup vs baseline: 3.7416x; 1.4191x over previous
//
#include <hip/hip_runtime.h>

// CapsNet conv + dynamic routing, single fused kernel (MI355X / gfx950).
// One block (1024 thr = 16 waves) per pixel; votes^T in the MFMA accumulator.
// R7: all intra-row cross-lane reductions moved from LDS-pipe shuffles
// (ds_bpermute) to VALU DPP ops — the R6 profile showed the LDS pipe
// (butterflies) as the serialization point while VALU sat at 24%.
//
// Lane decomposition (l = lane, q = l>>4, il = l&15), wave (wf, wi):
//   acc[tf][ti].r = votes[ i = 64*wi+16*ti+il ][ f = 64*wf+16*tf+4*q+r ]
//   c = 8*wf + 2*tf + (q>>1)   (capsule),  n = 4*(q&1) + r

#define BS 16
#define CI 256
#define CO 32
#define NO 8
#define HI 20
#define WI 20
#define HO 6
#define WO 6
#define NPIX 36
#define NTAP 81
#define XP 104          // k pitch (bf16), 2-way banks (free)
#define NBLK 576

typedef __attribute__((ext_vector_type(8))) short bf16x8;
typedef __attribute__((ext_vector_type(4))) float f32x4;

__device__ __forceinline__ ushort f2bf(float x) {
    union { float f; unsigned u; } v; v.f = x;
    unsigned r = v.u + 0x7FFFu + ((v.u >> 16) & 1u);   // RNE
    return (ushort)(r >> 16);
}

// VALU cross-lane add via DPP (no LDS pipe). bound_ctrl=true -> OOB reads 0.
template<int CTRL>
__device__ __forceinline__ float dpp_radd(float v) {
    int s = __builtin_amdgcn_update_dpp(0, __float_as_int(v), CTRL, 0xF, 0xF, true);
    return v + __int_as_float(s);
}
// Hillis-Steele scan within each 16-lane row; lane 15 ends with the row sum.
__device__ __forceinline__ float row16_sum_tail(float v) {
    v = dpp_radd<0x111>(v);   // row_shr:1
    v = dpp_radd<0x112>(v);   // row_shr:2
    v = dpp_radd<0x114>(v);   // row_shr:4
    v = dpp_radd<0x118>(v);   // row_shr:8
    return v;
}
// Full butterfly sum over aligned 8-lane groups (all lanes get the sum).
__device__ __forceinline__ float grp8_sum_all(float v) {
    v = dpp_radd<0xB1>(v);    // quad_perm [1,0,3,2]  (xor 1)
    v = dpp_radd<0x4E>(v);    // quad_perm [2,3,0,1]  (xor 2)
    v = dpp_radd<0x141>(v);   // row_half_mirror      (other quad)
    return v;
}

__global__ __launch_bounds__(1024) void caps_kernel(
    const float* __restrict__ x,     // [16,256,1,20,20]
    const float* __restrict__ Wt,    // [256,1,9,9]
    const float* __restrict__ bias,  // [32,8,1,1]
    float* __restrict__ out)         // [16,32,8,6,6]
{
    __shared__ __align__(16) ushort xw[CI * XP];        // 53248 B
    __shared__ __align__(16) ushort wl[CO * NO * XP];   // 53248 B
    __shared__ __align__(16) float  smx[4 * 256];       // softmax partials [wf][i]
    __shared__ __align__(16) float  pre[4 * 256];       // preact partials [wi][c*8+n]
    __shared__ __align__(16) float  act[256];           // activation broadcast

    const int t   = threadIdx.x, blk = blockIdx.x;
    const int b   = blk & 15;          // XCD-local image mapping
    const int hw  = blk >> 4;          // 0..35
    const int h   = hw / WO, w = hw % WO;
    const int w2  = 2 * w;

    const int wid = t >> 6, l = t & 63;
    const int q = l >> 4, il = l & 15;
    const int wf = wid >> 2, wi = wid & 3;

    // ---- stage W (k-major, pitch 104)
    for (int p = t; p < CO * NO * NTAP; p += 1024) {
        int f = p / NTAP, k = p - f * NTAP;
        wl[f * XP + k] = f2bf(Wt[p]);
    }
    // ---- zero pads k in [81,104) for both tiles
    {
        int i = t >> 2, s4 = t & 3;
        #pragma unroll
        for (int j = 0; j < 6; ++j) {
            int k = NTAP + s4 * 6 + j;
            if (k < XP) { xw[i * XP + k] = 0; wl[i * XP + k] = 0; }
        }
    }
    // ---- stage x window, coalesced float4 quads
    #pragma unroll
    for (int pass = 0; pass < 9; ++pass) {
        int idx = pass * 1024 + t;
        int q4 = idx & 3, r = idx >> 2;
        int kh = r % 9, i = r / 9;
        float4 v = *(const float4*)(x + ((b * CI + i) * HI + (2 * h + kh)) * WI + 4 * q4);
        const float* ve = &v.x;
        #pragma unroll
        for (int e = 0; e < 4; ++e) {
            int kw = 4 * q4 + e - w2;
            if ((unsigned)kw < 9u) xw[i * XP + kh * 9 + kw] = f2bf(ve[e]);
        }
    }
    if (w >= 4) {
        for (int r = t; r < CI * 9; r += 1024) {
            int kh = r % 9, i = r / 9;
            float4 v = *(const float4*)(x + ((b * CI + i) * HI + (2 * h + kh)) * WI + 16);
            const float* ve = &v.x;
            #pragma unroll
            for (int e = 0; e < 4; ++e) {
                int kw = 16 + e - w2;
                if ((unsigned)kw < 9u) xw[i * XP + kh * 9 + kw] = f2bf(ve[e]);
            }
        }
    }

    const float bias_r = (t < 256) ? bias[t] : 0.f;
    __syncthreads();

    // ---- conv via MFMA: votes^T
    f32x4 acc[4][4];
    #pragma unroll
    for (int tf = 0; tf < 4; ++tf)
        #pragma unroll
        for (int ti = 0; ti < 4; ++ti)
            acc[tf][ti] = (f32x4){0.f, 0.f, 0.f, 0.f};

    #pragma unroll
    for (int ks = 0; ks < 3; ++ks) {
        const int ko = ks * 32 + q * 8;
        bf16x8 af[4], bv[4];
        #pragma unroll
        for (int tf = 0; tf < 4; ++tf)
            af[tf] = *(const bf16x8*)&wl[(wf * 64 + tf * 16 + il) * XP + ko];
        #pragma unroll
        for (int ti = 0; ti < 4; ++ti)
            bv[ti] = *(const bf16x8*)&xw[(wi * 64 + ti * 16 + il) * XP + ko];
        #pragma unroll
        for (int tf = 0; tf < 4; ++tf)
            #pragma unroll
            for (int ti = 0; ti < 4; ++ti)
                acc[tf][ti] = __builtin_amdgcn_mfma_f32_16x16x32_bf16(
                    af[tf], bv[ti], acc[tf][ti], 0, 0, 0);
    }
    // No barrier: routing uses separate LDS buffers (smx/pre/act).

    // ---- dynamic routing, 3 iterations
    float lg[4][4];
    #pragma unroll
    for (int tf = 0; tf < 4; ++tf)
        #pragma unroll
        for (int ti = 0; ti < 4; ++ti) lg[tf][ti] = 0.f;

    #pragma unroll
    for (int it = 0; it < 3; ++it) {
        // --- preact partials pp[tf][r]
        float pp[4][4];
        if (it == 0) {
            #pragma unroll
            for (int tf = 0; tf < 4; ++tf)
                #pragma unroll
                for (int r = 0; r < 4; ++r)
                    pp[tf][r] = (acc[tf][0][r] + acc[tf][1][r]
                               + acc[tf][2][r] + acc[tf][3][r]) * 0.03125f;
        } else {
            float e[4][4], srow[4] = {0.f, 0.f, 0.f, 0.f};
            #pragma unroll
            for (int tf = 0; tf < 4; ++tf)
                #pragma unroll
                for (int ti = 0; ti < 4; ++ti) {
                    e[tf][ti] = __expf(lg[tf][ti]);
                    srow[ti] += e[tf][ti];
                }
            #pragma unroll
            for (int ti = 0; ti < 4; ++ti)
                srow[ti] += __shfl_xor(srow[ti], 32, 64);   // other c-half (q>>1)
            if (q == 0) {
                #pragma unroll
                for (int ti = 0; ti < 4; ++ti)
                    smx[wf * 256 + wi * 64 + ti * 16 + il] = srow[ti];
            }
            __syncthreads();
            float rtot[4];
            #pragma unroll
            for (int ti = 0; ti < 4; ++ti) {
                int i = wi * 64 + ti * 16 + il;
                rtot[ti] = __builtin_amdgcn_rcpf(
                    smx[i] + smx[256 + i] + smx[512 + i] + smx[768 + i]);
            }
            float route[4][4];
            #pragma unroll
            for (int tf = 0; tf < 4; ++tf)
                #pragma unroll
                for (int ti = 0; ti < 4; ++ti) route[tf][ti] = e[tf][ti] * rtot[ti];
            #pragma unroll
            for (int tf = 0; tf < 4; ++tf)
                #pragma unroll
                for (int r = 0; r < 4; ++r)
                    pp[tf][r] = route[tf][0] * acc[tf][0][r] + route[tf][1] * acc[tf][1][r]
                              + route[tf][2] * acc[tf][2][r] + route[tf][3] * acc[tf][3][r];
        }

        // --- reduce over il (16 i-lanes) on the VALU pipe (DPP)
        #pragma unroll
        for (int tf = 0; tf < 4; ++tf)
            #pragma unroll
            for (int r = 0; r < 4; ++r)
                pp[tf][r] = row16_sum_tail(pp[tf][r]);
        if (il == 15) {
            #pragma unroll
            for (int tf = 0; tf < 4; ++tf) {
                int c = wf * 8 + tf * 2 + (q >> 1);
                f32x4 vv = {pp[tf][0], pp[tf][1], pp[tf][2], pp[tf][3]};
                *(f32x4*)&pre[wi * 256 + c * 8 + (q & 1) * 4] = vv;
            }
        }
        __syncthreads();

        // --- finish preact + squash (threads 0..255), broadcast act
        if (t < 256) {
            float s = bias_r + pre[t] + pre[256 + t] + pre[512 + t] + pre[768 + t];
            float sq = grp8_sum_all(s * s);       // sum over the 8 n-lanes (DPP)
            float a = s * __builtin_amdgcn_sqrtf(sq) * __builtin_amdgcn_rcpf(1.f + sq);
            if (it == 2) {
                int c = t >> 3, n = t & 7;
                out[(((b * CO + c) * NO + n) * HO + h) * WO + w] = a;
            } else {
                act[t] = a;
            }
        }

        // --- distances -> logits (skip on last iter; no trailing barrier)
        if (it < 2) {
            __syncthreads();   // act ready
            #pragma unroll
            for (int tf = 0; tf < 4; ++tf) {
                int c = wf * 8 + tf * 2 + (q >> 1);
                f32x4 av = *(const f32x4*)&act[c * 8 + (q & 1) * 4];
                #pragma unroll
                for (int ti = 0; ti < 4; ++ti) {
                    float d = acc[tf][ti][0] * av[0] + acc[tf][ti][1] * av[1]
                            + acc[tf][ti][2] * av[2] + acc[tf][ti][3] * av[3];
                    d += __shfl_xor(d, 16, 64);   // other n-half
                    lg[tf][ti] += d;
                }
            }
        }
    }
}

extern "C" void kernel_launch(void* const* d_in, const int* in_sizes, int n_in,
                              void* d_out, int out_size, void* d_ws, size_t ws_size,
                              hipStream_t stream) {
    const float* x    = (const float*)d_in[0];
    const float* Wt   = (const float*)d_in[1];
    const float* bias = (const float*)d_in[2];
    float* out = (float*)d_out;
    caps_kernel<<<NBLK, 1024, 0, stream>>>(x, Wt, bias, out);
}